// Round 3
// baseline (410.318 us; speedup 1.0000x reference)
//
#include <hip/hip_runtime.h>

typedef __attribute__((ext_vector_type(8))) short short8;
typedef __attribute__((ext_vector_type(4))) short short4_t;
typedef __attribute__((ext_vector_type(4))) float float4_t;

#define NTOK 4096
#define CDIM 256
#define BPB (NTOK * CDIM)               /* elements per batch per tensor */
#define NROWS (4 * NTOK)                /* 16384 total rows */
#define C1 0.0901684400555602f          /* log2(e) / sqrt(256) */

__device__ inline float bf2f(short s) {
    return __uint_as_float(((unsigned)(unsigned short)s) << 16);
}
__device__ inline short f2bf(float f) {
    unsigned u = __float_as_uint(f);
    return (short)((u + 0x7fffu + ((u >> 16) & 1u)) >> 16);
}

// ---------------------------------------------------------------------------
// Dtype sniff (x ~ N(0,1)): bf16 dwords have sane exponents in bits[14:7].
// ---------------------------------------------------------------------------
__global__ void sniff_dtype(const unsigned* __restrict__ x, int* __restrict__ flag) {
    __shared__ int cnt;
    if (threadIdx.x == 0) cnt = 0;
    __syncthreads();
    int local = 0;
    for (int i = threadIdx.x; i < 1024; i += 256) {
        unsigned e = (x[i] >> 7) & 0xffu;
        if (e >= 100u && e <= 140u) local++;
    }
    atomicAdd(&cnt, local);
    __syncthreads();
    if (threadIdx.x == 0) flag[0] = (cnt >= 512) ? 1 : 0;
}

// ---------------------------------------------------------------------------
// QKV projection, d-split x2: each wg computes a [64 n x 128 d] slab for all
// three weights. Two interleaved MFMA chains (dt pairs) for ILP.
// ---------------------------------------------------------------------------
template <bool ISBF>
__device__ __forceinline__ void qkv_body(
    int b, int dh, const void* xv,
    const void* Wqv, const void* bqv,
    const void* Wkv, const void* bkv,
    const void* Wvv, const void* bvv,
    short* qdst, short* kdst, short* vtdst)
{
    const int n0 = blockIdx.x * 64;
    const int tid = threadIdx.x;
    const int w = tid >> 6, lane = tid & 63, l15 = lane & 15, qd = lane >> 4;

    __shared__ short xt[64 * 264];  // XT[n][c], stride 264

    {   // stage X tile transposed: thread tid owns channel c = tid
        const int c = tid;
        const size_t xb = (size_t)b * CDIM * NTOK + (size_t)c * NTOK + n0;
        if (ISBF) {
            const short* x = (const short*)xv;
            #pragma unroll
            for (int i = 0; i < 8; ++i) {
                short8 v = *(const short8*)(x + xb + i * 8);
                #pragma unroll
                for (int j = 0; j < 8; ++j) xt[(i * 8 + j) * 264 + c] = v[j];
            }
        } else {
            const float* x = (const float*)xv;
            #pragma unroll
            for (int i = 0; i < 16; ++i) {
                float4 v = *(const float4*)(x + xb + i * 4);
                xt[(i * 4 + 0) * 264 + c] = f2bf(v.x);
                xt[(i * 4 + 1) * 264 + c] = f2bf(v.y);
                xt[(i * 4 + 2) * 264 + c] = f2bf(v.z);
                xt[(i * 4 + 3) * 264 + c] = f2bf(v.w);
            }
        }
    }
    __syncthreads();

    short8 afrag[8];
    #pragma unroll
    for (int s = 0; s < 8; ++s)
        afrag[s] = *(const short8*)&xt[(16 * w + l15) * 264 + s * 32 + qd * 8];

    const void* Ws[3] = { Wqv, Wkv, Wvv };
    const void* bs[3] = { bqv, bkv, bvv };
    short* dsts[2] = { qdst, kdst };

    #pragma unroll
    for (int wi = 0; wi < 3; ++wi) {
        #pragma unroll
        for (int dtg = 0; dtg < 4; ++dtg) {
            const int dtA = dh * 8 + dtg * 2, dtB = dtA + 1;
            const int rowA = 16 * dtA + l15, rowB = rowA + 16;
            float4_t accA = {0.f, 0.f, 0.f, 0.f};
            float4_t accB = {0.f, 0.f, 0.f, 0.f};
            #pragma unroll
            for (int s = 0; s < 8; ++s) {
                short8 bfA, bfB;
                if (ISBF) {
                    const short* Wp = (const short*)Ws[wi];
                    bfA = *(const short8*)(Wp + rowA * 256 + s * 32 + qd * 8);
                    bfB = *(const short8*)(Wp + rowB * 256 + s * 32 + qd * 8);
                } else {
                    const float* Wf = (const float*)Ws[wi];
                    const float* pA = Wf + rowA * 256 + s * 32 + qd * 8;
                    const float* pB = Wf + rowB * 256 + s * 32 + qd * 8;
                    float4 a0 = *(const float4*)pA, a1 = *(const float4*)(pA + 4);
                    float4 b0 = *(const float4*)pB, b1 = *(const float4*)(pB + 4);
                    bfA[0]=f2bf(a0.x); bfA[1]=f2bf(a0.y); bfA[2]=f2bf(a0.z); bfA[3]=f2bf(a0.w);
                    bfA[4]=f2bf(a1.x); bfA[5]=f2bf(a1.y); bfA[6]=f2bf(a1.z); bfA[7]=f2bf(a1.w);
                    bfB[0]=f2bf(b0.x); bfB[1]=f2bf(b0.y); bfB[2]=f2bf(b0.z); bfB[3]=f2bf(b0.w);
                    bfB[4]=f2bf(b1.x); bfB[5]=f2bf(b1.y); bfB[6]=f2bf(b1.z); bfB[7]=f2bf(b1.w);
                }
                accA = __builtin_amdgcn_mfma_f32_16x16x32_bf16(afrag[s], bfA, accA, 0, 0, 0);
                accB = __builtin_amdgcn_mfma_f32_16x16x32_bf16(afrag[s], bfB, accB, 0, 0, 0);
            }
            const float biasA = ISBF ? bf2f(((const short*)bs[wi])[rowA])
                                     : ((const float*)bs[wi])[rowA];
            const float biasB = ISBF ? bf2f(((const short*)bs[wi])[rowB])
                                     : ((const float*)bs[wi])[rowB];
            if (wi < 2) {
                short* dst = dsts[wi];
                #pragma unroll
                for (int r = 0; r < 4; ++r) {
                    const int n = n0 + 16 * w + 4 * qd + r;
                    dst[(size_t)n * 256 + rowA] = f2bf(accA[r] + biasA);
                    dst[(size_t)n * 256 + rowB] = f2bf(accB[r] + biasB);
                }
            } else {
                short4_t pkA, pkB;
                #pragma unroll
                for (int r = 0; r < 4; ++r) { pkA[r] = f2bf(accA[r] + biasA);
                                              pkB[r] = f2bf(accB[r] + biasB); }
                const int n = n0 + 16 * w + 4 * qd;
                *(short4_t*)(vtdst + (size_t)rowA * NTOK + n) = pkA;
                *(short4_t*)(vtdst + (size_t)rowB * NTOK + n) = pkB;
            }
        }
    }
}

__global__ __launch_bounds__(256, 2) void qkv_proj(
    int b0, const void* xv, const void* Wq, const void* bq,
    const void* Wk, const void* bk, const void* Wv, const void* bv,
    const int* __restrict__ flag,
    short* qbase, short* kbase, short* vtbase)
{
    const int dh = blockIdx.y;
    const int bl = blockIdx.z, b = b0 + bl;
    short* qdst  = qbase  + (size_t)b  * BPB;
    short* kdst  = kbase  + (size_t)bl * BPB;
    short* vtdst = vtbase + (size_t)bl * BPB;
    if (flag[0]) qkv_body<true >(b, dh, xv, Wq, bq, Wk, bk, Wv, bv, qdst, kdst, vtdst);
    else         qkv_body<false>(b, dh, xv, Wq, bq, Wk, bk, Wv, bv, qdst, kdst, vtdst);
}

// ---------------------------------------------------------------------------
// Flash attention inner loop (shared by partial & full variants).
// ---------------------------------------------------------------------------
#define FLASH_PROLOGUE()                                                      \
    const int tid = threadIdx.x;                                              \
    const int w = tid >> 6, lane = tid & 63, l15 = lane & 15, qd = lane >> 4; \
    __shared__ short smem[18432 + 4608];                                      \
    short* kv   = smem;                                                       \
    short* pbuf = smem + 18432;                                               \
    short8 qf[8];                                                             \
    {                                                                         \
        const size_t qrow = (size_t)(q0 + 16 * w + l15) * 256;                \
        _Pragma("unroll")                                                     \
        for (int s = 0; s < 8; ++s)                                           \
            qf[s] = *(const short8*)(Q + qrow + s * 32 + qd * 8);             \
    }                                                                         \
    float4_t oacc[16];                                                        \
    _Pragma("unroll")                                                         \
    for (int dt = 0; dt < 16; ++dt) oacc[dt] = {0.f, 0.f, 0.f, 0.f};          \
    float m_run[4] = { -INFINITY, -INFINITY, -INFINITY, -INFINITY };          \
    float l_run[4] = { 0.f, 0.f, 0.f, 0.f };

#define FLASH_KT_ITER(k0)                                                     \
    __syncthreads();                                                          \
    _Pragma("unroll")                                                         \
    for (int i = 0; i < 8; ++i) {                                             \
        const int id = i * 256 + tid;                                         \
        const int r = id >> 5, j = id & 31;                                   \
        short8 v = *(const short8*)(K + (size_t)((k0) + r) * 256 + j * 8);    \
        *(short8*)&kv[r * 264 + j * 8] = v;                                   \
    }                                                                         \
    __syncthreads();                                                          \
    float4_t sacc[4];                                                         \
    _Pragma("unroll")                                                         \
    for (int tn = 0; tn < 4; ++tn) {                                          \
        sacc[tn] = {0.f, 0.f, 0.f, 0.f};                                      \
        _Pragma("unroll")                                                     \
        for (int s = 0; s < 8; ++s) {                                         \
            short8 bf = *(const short8*)&kv[(tn*16 + l15)*264 + s*32 + qd*8]; \
            sacc[tn] = __builtin_amdgcn_mfma_f32_16x16x32_bf16(qf[s], bf, sacc[tn], 0, 0, 0); \
        }                                                                     \
    }                                                                         \
    float p[4][4], alpha[4];                                                  \
    _Pragma("unroll")                                                         \
    for (int r = 0; r < 4; ++r) {                                             \
        float m = sacc[0][r];                                                 \
        _Pragma("unroll")                                                     \
        for (int tn = 1; tn < 4; ++tn) m = fmaxf(m, sacc[tn][r]);             \
        _Pragma("unroll")                                                     \
        for (int msk = 1; msk < 16; msk <<= 1)                                \
            m = fmaxf(m, __shfl_xor(m, msk, 64));                             \
        const float mnew = fmaxf(m_run[r], m);                                \
        alpha[r] = exp2f((m_run[r] - mnew) * C1);                             \
        m_run[r] = mnew;                                                      \
        float lsum = 0.f;                                                     \
        _Pragma("unroll")                                                     \
        for (int tn = 0; tn < 4; ++tn) {                                      \
            const float pv = exp2f((sacc[tn][r] - mnew) * C1);                \
            p[tn][r] = pv;                                                    \
            lsum += pv;                                                       \
        }                                                                     \
        _Pragma("unroll")                                                     \
        for (int msk = 1; msk < 16; msk <<= 1)                                \
            lsum += __shfl_xor(lsum, msk, 64);                                \
        l_run[r] = l_run[r] * alpha[r] + lsum;                                \
    }                                                                         \
    {   /* wave-uniform skip of rescale when all alpha == 1 */                \
        bool need = (alpha[0] < 1.f) || (alpha[1] < 1.f) ||                   \
                    (alpha[2] < 1.f) || (alpha[3] < 1.f);                     \
        if (__any(need)) {                                                    \
            _Pragma("unroll")                                                 \
            for (int dt = 0; dt < 16; ++dt) {                                 \
                _Pragma("unroll")                                             \
                for (int r = 0; r < 4; ++r) oacc[dt][r] *= alpha[r];          \
            }                                                                 \
        }                                                                     \
    }                                                                         \
    _Pragma("unroll")                                                         \
    for (int tn = 0; tn < 4; ++tn) {                                          \
        _Pragma("unroll")                                                     \
        for (int r = 0; r < 4; ++r)                                           \
            pbuf[(w*16 + 4*qd + r)*72 + tn*16 + l15] = f2bf(p[tn][r]);        \
    }                                                                         \
    /* own-wave P A-frags: rows w*16.. written by this wave only */           \
    short8 pa[2];                                                             \
    _Pragma("unroll")                                                         \
    for (int ks = 0; ks < 2; ++ks)                                            \
        pa[ks] = *(const short8*)&pbuf[(w*16 + l15)*72 + ks*32 + qd*8];       \
    __syncthreads();                                                          \
    _Pragma("unroll")                                                         \
    for (int i = 0; i < 8; ++i) {                                             \
        const int id = i * 256 + tid;                                         \
        const int d = id >> 3, j = id & 7;                                    \
        short8 v = *(const short8*)(VT + (size_t)d * NTOK + (k0) + j * 8);    \
        *(short8*)&kv[d * 72 + j * 8] = v;                                    \
    }                                                                         \
    __syncthreads();                                                          \
    _Pragma("unroll")                                                         \
    for (int dt = 0; dt < 16; ++dt) {                                         \
        _Pragma("unroll")                                                     \
        for (int ks = 0; ks < 2; ++ks) {                                      \
            short8 bf = *(const short8*)&kv[(dt*16 + l15)*72 + ks*32 + qd*8]; \
            oacc[dt] = __builtin_amdgcn_mfma_f32_16x16x32_bf16(pa[ks], bf, oacc[dt], 0, 0, 0); \
        }                                                                     \
    }

// Partial variant: key range [kt0,kt1), writes unnormalized O + (m,l) fp32.
__global__ __launch_bounds__(256, 3) void flash_part(
    const short* qbase, const short* kbase, const short* vtbase,
    float* __restrict__ pm, float* __restrict__ pl, float* __restrict__ pO)
{
    const int qt = blockIdx.x, sk = blockIdx.y, b = blockIdx.z;
    const int split = gridDim.y;
    const int q0 = qt * 64;
    const short* Q  = qbase  + (size_t)b * BPB;
    const short* K  = kbase  + (size_t)b * BPB;
    const short* VT = vtbase + (size_t)b * BPB;

    FLASH_PROLOGUE();

    const int kt0 = (64 * sk) / split, kt1 = (64 * (sk + 1)) / split;
    for (int kt = kt0; kt < kt1; ++kt) {
        const int k0 = kt * 64;
        FLASH_KT_ITER(k0);
    }

    const int rbase = (b * 64 + qt) * 64 + 16 * w + 4 * qd;
    if (l15 == 0) {
        #pragma unroll
        for (int r = 0; r < 4; ++r) {
            pm[(size_t)sk * NROWS + rbase + r] = m_run[r];
            pl[(size_t)sk * NROWS + rbase + r] = l_run[r];
        }
    }
    #pragma unroll
    for (int dt = 0; dt < 16; ++dt) {
        #pragma unroll
        for (int r = 0; r < 4; ++r)
            pO[(size_t)sk * NROWS * 256 + (size_t)(rbase + r) * 256 + 16 * dt + l15] =
                oacc[dt][r];
    }
}

// Full variant (fallback when ws can't hold partials).
__global__ __launch_bounds__(256, 1) void flash_full(
    int b0, const short* qbase, const short* kbase, const short* vtbase,
    const int* __restrict__ flag, void* outv)
{
    const int qt = blockIdx.x;
    const int bl = blockIdx.y, b = b0 + bl;
    const int q0 = qt * 64;
    const short* Q  = qbase  + (size_t)b  * BPB;
    const short* K  = kbase  + (size_t)bl * BPB;
    const short* VT = vtbase + (size_t)bl * BPB;

    FLASH_PROLOGUE();

    for (int kt = 0; kt < 64; ++kt) {
        const int k0 = kt * 64;
        FLASH_KT_ITER(k0);
    }

    const int isbf = flag[0];
    float inv[4];
    #pragma unroll
    for (int r = 0; r < 4; ++r) inv[r] = 1.0f / l_run[r];
    #pragma unroll
    for (int dt = 0; dt < 16; ++dt) {
        #pragma unroll
        for (int r = 0; r < 4; ++r) {
            const size_t o =
                (size_t)(b * NTOK + q0 + 16 * w + 4 * qd + r) * 256 + dt * 16 + l15;
            const float val = oacc[dt][r] * inv[r];
            if (isbf) ((short*)outv)[o] = f2bf(val);
            else      ((float*)outv)[o] = val;
        }
    }
}

// ---------------------------------------------------------------------------
// Combine: merge `split` partials per row. out = sum a_s O_s / sum a_s l_s.
// ---------------------------------------------------------------------------
__global__ __launch_bounds__(256) void combine(
    int split, const float* __restrict__ pm, const float* __restrict__ pl,
    const float* __restrict__ pO, const int* __restrict__ flag, void* outv)
{
    const int qt = blockIdx.x, b = blockIdx.y;
    const int tid = threadIdx.x;
    const int row = tid >> 2, seg = tid & 3;
    const int ridx = (b * 64 + qt) * 64 + row;

    float mv[3], a[3];
    float mx = -INFINITY;
    for (int s = 0; s < split; ++s) {
        mv[s] = pm[(size_t)s * NROWS + ridx];
        mx = fmaxf(mx, mv[s]);
    }
    float denom = 0.f;
    for (int s = 0; s < split; ++s) {
        a[s] = exp2f((mv[s] - mx) * C1);
        denom += a[s] * pl[(size_t)s * NROWS + ridx];
    }
    const float inv = 1.0f / denom;
    const int isbf = flag[0];

    const size_t obase = (size_t)ridx * 256 + seg * 64;
    #pragma unroll
    for (int j = 0; j < 8; ++j) {
        float4_t v0 = {0.f,0.f,0.f,0.f}, v1 = {0.f,0.f,0.f,0.f};
        for (int s = 0; s < split; ++s) {
            const float4_t* Os = (const float4_t*)(pO + (size_t)s * NROWS * 256 + obase);
            v0 += a[s] * Os[2 * j];
            v1 += a[s] * Os[2 * j + 1];
        }
        v0 *= inv; v1 *= inv;
        if (isbf) {
            short8 pk;
            #pragma unroll
            for (int t = 0; t < 4; ++t) { pk[t] = f2bf(v0[t]); pk[4 + t] = f2bf(v1[t]); }
            *(short8*)((short*)outv + obase + j * 8) = pk;
        } else {
            float4_t* op = (float4_t*)((float*)outv + obase);
            op[2 * j] = v0; op[2 * j + 1] = v1;
        }
    }
}

extern "C" void kernel_launch(void* const* d_in, const int* in_sizes, int n_in,
                              void* d_out, int out_size, void* d_ws, size_t ws_size,
                              hipStream_t stream)
{
    const size_t HDR = 256;
    const size_t TB  = (size_t)BPB * 2;            // 2 MB per batch per tensor
    const size_t PO  = (size_t)NROWS * 256 * 4;    // 16 MB per split partial
    const size_t PM  = (size_t)NROWS * 4;          // 64 KB
    const size_t avail = ws_size > HDR ? ws_size - HDR : 0;

    int split = 0;  // 0 = no-split fallback
    if      (avail >= 12 * TB + 3 * (PO + 2 * PM)) split = 3;
    else if (avail >= 12 * TB + 2 * (PO + 2 * PM)) split = 2;

    int*   flag   = (int*)d_ws;
    short* kbase  = (short*)((char*)d_ws + HDR);

    sniff_dtype<<<1, 256, 0, stream>>>((const unsigned*)d_in[0], flag);

    if (split >= 2) {
        short* vtbase = kbase + 4 * (size_t)BPB;
        short* qbase  = vtbase + 4 * (size_t)BPB;
        float* pm = (float*)(qbase + 4 * (size_t)BPB);
        float* pl = pm + (size_t)split * NROWS;
        float* pO = pl + (size_t)split * NROWS;
        qkv_proj<<<dim3(64, 2, 4), 256, 0, stream>>>(
            0, d_in[0], d_in[1], d_in[2], d_in[3], d_in[4], d_in[5], d_in[6],
            flag, qbase, kbase, vtbase);
        flash_part<<<dim3(64, split, 4), 256, 0, stream>>>(
            qbase, kbase, vtbase, pm, pl, pO);
        combine<<<dim3(64, 4), 256, 0, stream>>>(split, pm, pl, pO, flag, d_out);
        return;
    }

    // Fallbacks (small ws): single-pass flash, optionally batch-chunked.
    const bool q_in_ws = avail >= 12 * TB;
    int nb = 4;
    if (!q_in_ws) {
        size_t fit = avail / (2 * TB);
        nb = fit >= 4 ? 4 : (fit < 1 ? 1 : (int)fit);
    }
    short* vtbase = kbase + (size_t)nb * BPB;
    short* qbase  = q_in_ws ? (vtbase + (size_t)nb * BPB) : (short*)d_out;

    for (int b0 = 0; b0 < 4; b0 += nb) {
        const int nbc = (4 - b0) < nb ? (4 - b0) : nb;
        qkv_proj<<<dim3(64, 2, nbc), 256, 0, stream>>>(
            b0, d_in[0], d_in[1], d_in[2], d_in[3], d_in[4], d_in[5], d_in[6],
            flag, qbase, kbase, vtbase);
        flash_full<<<dim3(64, nbc), 256, 0, stream>>>(
            b0, qbase, kbase, vtbase, flag, d_out);
    }
}